// Round 1
// 266.174 us; speedup vs baseline: 1.0148x; 1.0148x over previous
//
#include <hip/hip_runtime.h>
#include <math.h>

// Time2Vec: out[b,l,d,e] = (e==0) ? x*W[d,0]+b[d,0] : sin(x*W[d,e]+b[d,e])
// B=16, L=8192, D=8, E=64. Output fp32, 67,108,864 elements (256 MiB).
// Memory-bound: ~260 MB HBM traffic -> ~41 us floor at the fill kernel's
// demonstrated 6.56 TB/s write bandwidth.
//
// v2 change vs the 270 us version: the runtime-trip-count grid-stride loop
// kept exactly ONE x-load in flight per wave (load -> vmcnt(0) -> fma/sin ->
// store, 8 serial chains). Here each block owns a contiguous BLOCK*ITERS
// float4 chunk with ITERS known at compile time: all 8 x-loads are hoisted
// and issued back-to-back (8 outstanding, compiler emits descending vmcnt
// waits), then each slice computes and stores. Stores are nontemporal --
// the 256 MiB output stream is never re-read, so don't write-allocate L2.
//
// Layout invariant (unchanged): within a block the float4-index stride is
// 256, i.e. 16 rows, and 16 % 8 == 0 -> each thread's (d, quad) coords are
// fixed, so W[d][quad*4..] / b[d][quad*4..] live in 8 registers for the
// whole kernel. Each wave store instruction covers 1 KiB contiguous.

typedef float f32x4 __attribute__((ext_vector_type(4)));

__device__ __forceinline__ f32x4 t2v_point(float xv, f32x4 w4, f32x4 b4, bool keep0)
{
    xv = (xv != xv) ? 0.0f : xv;     // nan_to_num
    f32x4 y;
    y.x = fmaf(xv, w4.x, b4.x);
    y.y = fmaf(xv, w4.y, b4.y);
    y.z = fmaf(xv, w4.z, b4.z);
    y.w = fmaf(xv, w4.w, b4.w);
    y.x = keep0 ? y.x : __sinf(y.x); // global e==0 passes through affine
    y.y = __sinf(y.y);
    y.z = __sinf(y.z);
    y.w = __sinf(y.w);
    return y;
}

template<int ITERS>
__global__ __launch_bounds__(256) void t2v_kernel_unrolled(
    const float* __restrict__ x,
    const float* __restrict__ W,   // (8, 64)
    const float* __restrict__ b,   // (8, 64)
    float* __restrict__ out)
{
    constexpr int BLOCK = 256;
    // Block owns float4s [blockIdx*BLOCK*ITERS, +BLOCK*ITERS); thread t
    // handles base + k*BLOCK for k in [0, ITERS). Chunk size 2048 float4s
    // = 128 rows (= 0 mod 8 rows), so d and quad are per-thread constants.
    const int base = blockIdx.x * (BLOCK * ITERS) + threadIdx.x;
    const int quad = base & 15;                 // float4 index within E=64
    const int d    = (base >> 4) & 7;           // D index

    const f32x4 w4 = reinterpret_cast<const f32x4*>(W)[d * 16 + quad];
    const f32x4 b4 = reinterpret_cast<const f32x4*>(b)[d * 16 + quad];
    const bool keep0 = (quad == 0);

    // Issue all ITERS x-loads up front: addresses are independent of load
    // results, so the wave keeps ITERS loads outstanding instead of 1.
    float xv[ITERS];
#pragma unroll
    for (int k = 0; k < ITERS; ++k)
        xv[k] = x[(base + k * BLOCK) >> 4];

#pragma unroll
    for (int k = 0; k < ITERS; ++k) {
        const f32x4 y = t2v_point(xv[k], w4, b4, keep0);
        __builtin_nontemporal_store(y, reinterpret_cast<f32x4*>(out) + base + k * BLOCK);
    }
}

// Fallback for shapes that don't divide evenly (kept from v1; unchanged).
__global__ __launch_bounds__(256) void t2v_kernel_gs(
    const float* __restrict__ x,
    const float* __restrict__ W,
    const float* __restrict__ b,
    float* __restrict__ out,
    int n_f4)
{
    const int tid    = blockIdx.x * blockDim.x + threadIdx.x;
    const int stride = gridDim.x * blockDim.x;
    const int quad   = tid & 15;
    const int d      = (tid >> 4) & 7;

    const f32x4 w4 = reinterpret_cast<const f32x4*>(W)[d * 16 + quad];
    const f32x4 b4 = reinterpret_cast<const f32x4*>(b)[d * 16 + quad];
    const bool keep0 = (quad == 0);

    for (int gid = tid; gid < n_f4; gid += stride) {
        const f32x4 y = t2v_point(x[gid >> 4], w4, b4, keep0);
        reinterpret_cast<f32x4*>(out)[gid] = y;
    }
}

extern "C" void kernel_launch(void* const* d_in, const int* in_sizes, int n_in,
                              void* d_out, int out_size, void* d_ws, size_t ws_size,
                              hipStream_t stream) {
    const float* x = (const float*)d_in[0];
    const float* W = (const float*)d_in[1];
    const float* b = (const float*)d_in[2];
    float* out = (float*)d_out;

    const int n_f4  = out_size / 4;   // 16,777,216 float4 stores (empirically
                                      // correct scaling from the passing v1)
    constexpr int BLOCK = 256;
    constexpr int ITERS = 8;
    constexpr int CHUNK = BLOCK * ITERS;   // 2048 float4s per block

    if (n_f4 % CHUNK == 0) {
        const int grid = n_f4 / CHUNK;     // 8192 blocks for this shape
        t2v_kernel_unrolled<ITERS><<<grid, BLOCK, 0, stream>>>(x, W, b, out);
    } else {
        t2v_kernel_gs<<<8192, BLOCK, 0, stream>>>(x, W, b, out, n_f4);
    }
}